// Round 6
// baseline (38.554 us; speedup 1.0000x reference)
//
#include <hip/hip_runtime.h>
#include <hip/hip_bf16.h>

#define B_SZ 4096
#define N_SZ 8192
#define D_SZ 128
#define CT 16                      // 32-col tiles per strip (512 cols)
#define NSTRIP (N_SZ / (CT * 32))  // 16 col strips

constexpr float TEMP = 0.5f;
constexpr float EPS = 1e-8f;
// exp(dot/TEMP) = exp2(dot * log2(e)/TEMP); sqrt of the scale folded into
// BOTH normalized vectors so the MFMA accumulator is directly the exp2 arg.
constexpr float SQS = 1.6986436006556212f;  // sqrt(log2(e)/TEMP)

typedef short short8 __attribute__((ext_vector_type(8)));
typedef float f32x16 __attribute__((ext_vector_type(16)));

// Tiled pn layout (bf16): byte addr of element (row r, col d) =
//   (r>>5)*8192 + (d>>3)*512 + (r&31)*16 + (d&7)*2
// -> each MFMA fragment chunk is 512B contiguous across 32 lanes; a whole
//    32-row tile is one contiguous 8KB block.

// ---------------------------------------------------------------------------
// Kernel A: per wave, handle row pair (r, r+B). Normalize into tiled-bf16 pn
// (scaled by SQS); exact-f32 positive-pair term -> posbuf[block];
// selfexp[r] = exp2(self-sim of the ROUNDED bf16 row) for later diag removal.
// ---------------------------------------------------------------------------
__global__ void norm_pos_kernel(const float* __restrict__ z_i,
                                const float* __restrict__ z_j,
                                unsigned int* __restrict__ pn_u32,
                                float* __restrict__ posbuf,
                                float* __restrict__ selfexp) {
    __shared__ float sp[4];
    int wid = threadIdx.x >> 6;
    int lane = threadIdx.x & 63;
    int r = blockIdx.x * 4 + wid;                 // [0, B)
    float2 vi = *reinterpret_cast<const float2*>(z_i + (size_t)r * D_SZ + lane * 2);
    float2 vj = *reinterpret_cast<const float2*>(z_j + (size_t)r * D_SZ + lane * 2);
    float ssi = vi.x * vi.x + vi.y * vi.y;
    float ssj = vj.x * vj.x + vj.y * vj.y;
    float dot = vi.x * vj.x + vi.y * vj.y;
#pragma unroll
    for (int m = 32; m >= 1; m >>= 1) {
        ssi += __shfl_xor(ssi, m, 64);
        ssj += __shfl_xor(ssj, m, 64);
        dot += __shfl_xor(dot, m, 64);
    }
    float ni = fmaxf(sqrtf(ssi), EPS);
    float nj = fmaxf(sqrtf(ssj), EPS);
    float si = SQS / ni, sj = SQS / nj;
    union { unsigned int u32; __hip_bfloat16 h[2]; } pki, pkj;
    pki.h[0] = __float2bfloat16(vi.x * si);
    pki.h[1] = __float2bfloat16(vi.y * si);
    pkj.h[0] = __float2bfloat16(vj.x * sj);
    pkj.h[1] = __float2bfloat16(vj.y * sj);
    // tiled store: lane l holds cols 2l, 2l+1 (one u32)
    int u = ((r >> 5) * 2048) + ((lane >> 2) * 128) + ((r & 31) * 4) + (lane & 3);
    pn_u32[u] = pki.u32;
    int r2 = r + B_SZ;
    int u2 = ((r2 >> 5) * 2048) + ((lane >> 2) * 128) + ((r2 & 31) * 4) + (lane & 3);
    pn_u32[u2] = pkj.u32;
    // self-similarity of the rounded rows (exp2 units, same scale as MFMA)
    float bx = __bfloat162float(pki.h[0]), by = __bfloat162float(pki.h[1]);
    float cx = __bfloat162float(pkj.h[0]), cy = __bfloat162float(pkj.h[1]);
    float sdi = bx * bx + by * by;
    float sdj = cx * cx + cy * cy;
#pragma unroll
    for (int m = 32; m >= 1; m >>= 1) {
        sdi += __shfl_xor(sdi, m, 64);
        sdj += __shfl_xor(sdj, m, 64);
    }
    if (lane == 0) {
        selfexp[r] = __builtin_amdgcn_exp2f(sdi);
        selfexp[r2] = __builtin_amdgcn_exp2f(sdj);
        sp[wid] = -dot / (ni * nj * TEMP) / (float)B_SZ;
    }
    __syncthreads();
    if (threadIdx.x == 0)
        posbuf[blockIdx.x] = sp[0] + sp[1] + sp[2] + sp[3];
}

// ---------------------------------------------------------------------------
// Kernel B: partial[r][strip] = sum over the strip's 512 cols of exp2(sim)
// (diagonal INCLUDED — removed later via selfexp).
// Block = 4 waves x 2 row-tiles (256 rows) x 512-col strip.
// TRIPLE-buffered LDS staging with COUNTED vmcnt (T3+T4): per tile, issue
// stage(t+2), compute tile t, s_waitcnt vmcnt(2) (drains only stage t+1,
// stage t+2 stays in flight ACROSS the barrier), raw s_barrier. No vmcnt(0)
// drain in steady state. C/D: col=lane&31, row=(reg&3)+8*(reg>>2)+4*(lane>>5).
// ---------------------------------------------------------------------------
__global__ __launch_bounds__(256, 2)
void simexp_kernel(const char* __restrict__ p, float* __restrict__ partial) {
    __shared__ char smem[3][8192];
    int wid = threadIdx.x >> 6;
    int lane = threadIdx.x & 63;
    int half = lane >> 5, lc = lane & 31;
    int rt0 = blockIdx.x * 8 + wid * 2;   // wave owns row-tiles rt0, rt0+1
    int ct0 = blockIdx.y * CT;

    // A fragments: coalesced 1KB loads, held for the whole kernel
    const char* afrag = p + (size_t)rt0 * 8192 + half * 512 + lc * 16;
    short8 a0[8], a1[8];
#pragma unroll
    for (int kc = 0; kc < 8; ++kc) {
        a0[kc] = *reinterpret_cast<const short8*>(afrag + kc * 1024);
        a1[kc] = *reinterpret_cast<const short8*>(afrag + 8192 + kc * 1024);
    }

    float rs0[16], rs1[16];
#pragma unroll
    for (int i = 0; i < 16; ++i) { rs0[i] = 0.0f; rs1[i] = 0.0f; }

    // stage one 8KB col-tile into LDS buffer: 2 global_load_lds per wave
    auto stage = [&](int buf, int ct) {
#pragma unroll
        for (int i = 0; i < 2; ++i) {
            int seg = i * 4 + wid;
            const char* g = p + (size_t)ct * 8192 + seg * 1024 + lane * 16;
            __builtin_amdgcn_global_load_lds(
                (const __attribute__((address_space(1))) unsigned int*)g,
                (__attribute__((address_space(3))) unsigned int*)&smem[buf][seg * 1024],
                16, 0, 0);
        }
    };

    // prologue: fill buffers 0 and 1; wait only for buffer 0 (vmcnt(2))
    stage(0, ct0);
    stage(1, ct0 + 1);
    asm volatile("s_waitcnt vmcnt(2)" ::: "memory");
    __builtin_amdgcn_s_barrier();
    __builtin_amdgcn_sched_barrier(0);

    int rb = 0, sb = 2;  // read buffer, stage buffer (rotating mod 3)
#pragma unroll 1
    for (int t = 0; t < CT; ++t) {
        if (t + 2 < CT) stage(sb, ct0 + t + 2);
        const char* bb = &smem[rb][0] + half * 512 + lc * 16;
        short8 b[8];
#pragma unroll
        for (int kc = 0; kc < 8; ++kc)
            b[kc] = *reinterpret_cast<const short8*>(bb + kc * 1024);
        f32x16 acc0 = {}, acc1 = {};
#pragma unroll
        for (int kc = 0; kc < 8; ++kc) {
            acc0 = __builtin_amdgcn_mfma_f32_32x32x16_bf16(a0[kc], b[kc], acc0, 0, 0, 0);
            acc1 = __builtin_amdgcn_mfma_f32_32x32x16_bf16(a1[kc], b[kc], acc1, 0, 0, 0);
        }
#pragma unroll
        for (int r = 0; r < 16; ++r) {
            rs0[r] += __builtin_amdgcn_exp2f(acc0[r]);
            rs1[r] += __builtin_amdgcn_exp2f(acc1[r]);
        }
        // counted wait: stage(t+1) must be done; stage(t+2) stays in flight
        if (t < CT - 2) {
            asm volatile("s_waitcnt vmcnt(2)" ::: "memory");
        } else {
            asm volatile("s_waitcnt vmcnt(0)" ::: "memory");
        }
        __builtin_amdgcn_s_barrier();
        __builtin_amdgcn_sched_barrier(0);
        rb = (rb == 2) ? 0 : rb + 1;
        sb = (sb == 2) ? 0 : sb + 1;
    }

    // reduce across the 32 column lanes
#pragma unroll
    for (int m = 1; m <= 16; m <<= 1) {
#pragma unroll
        for (int r = 0; r < 16; ++r) {
            rs0[r] += __shfl_xor(rs0[r], m, 64);
            rs1[r] += __shfl_xor(rs1[r], m, 64);
        }
    }
    if (lc == 0) {
        int strip = blockIdx.y;
#pragma unroll
        for (int r = 0; r < 16; ++r) {
            int lrow = (r & 3) + 8 * (r >> 2) + 4 * half;
            partial[(size_t)(rt0 * 32 + lrow) * NSTRIP + strip] = rs0[r];
            partial[(size_t)((rt0 + 1) * 32 + lrow) * NSTRIP + strip] = rs1[r];
        }
    }
}

// ---------------------------------------------------------------------------
// Kernel C: loss = sum(log(rowsum - selfexp))/2B + pos partials.
// 128 blocks x 64 threads; partial is [row][strip] -> 64B contiguous/thread.
// ---------------------------------------------------------------------------
__global__ void lse_kernel(const float* __restrict__ partial,
                           const float* __restrict__ selfexp,
                           const float* __restrict__ posbuf,
                           float* __restrict__ out) {
    int r = blockIdx.x * 64 + threadIdx.x;
    const float4* pr = reinterpret_cast<const float4*>(partial + (size_t)r * NSTRIP);
    float4 q0 = pr[0], q1 = pr[1], q2 = pr[2], q3 = pr[3];
    float s = (q0.x + q0.y + q0.z + q0.w) + (q1.x + q1.y + q1.z + q1.w) +
              (q2.x + q2.y + q2.z + q2.w) + (q3.x + q3.y + q3.z + q3.w);
    s -= selfexp[r];
    float v = __logf(s) * (1.0f / (float)N_SZ);
#pragma unroll
    for (int m = 32; m >= 1; m >>= 1) v += __shfl_xor(v, m, 64);
    if (threadIdx.x == 0) {
        float ps = 0.0f;
#pragma unroll
        for (int k = 0; k < 8; ++k) ps += posbuf[blockIdx.x * 8 + k];
        atomicAdd(out, v + ps);
    }
}

// ---------------------------------------------------------------------------
extern "C" void kernel_launch(void* const* d_in, const int* in_sizes, int n_in,
                              void* d_out, int out_size, void* d_ws, size_t ws_size,
                              hipStream_t stream) {
    const float* z_i = (const float*)d_in[0];
    const float* z_j = (const float*)d_in[1];
    float* out = (float*)d_out;
    char* ws = (char*)d_ws;

    unsigned int* pn = (unsigned int*)ws;                            // 2 MiB
    float* partial = (float*)(ws + (size_t)N_SZ * D_SZ * 2);         // 512 KiB
    float* selfexp = partial + (size_t)NSTRIP * N_SZ;                // 32 KiB
    float* posbuf = selfexp + N_SZ;                                  // 4 KiB

    hipMemsetAsync(out, 0, sizeof(float), stream);

    norm_pos_kernel<<<B_SZ / 4, 256, 0, stream>>>(z_i, z_j, pn, posbuf, selfexp);

    dim3 grid(N_SZ / 256, NSTRIP);  // 32 x 16 = 512 blocks
    simexp_kernel<<<grid, 256, 0, stream>>>((const char*)pn, partial);

    lse_kernel<<<N_SZ / 64, 64, 0, stream>>>(partial, selfexp, posbuf, out);
}

// Round 7
// 34.573 us; speedup vs baseline: 1.1151x; 1.1151x over previous
//
#include <hip/hip_runtime.h>
#include <hip/hip_bf16.h>

#define B_SZ 4096
#define N_SZ 8192
#define D_SZ 128
#define CT 16                      // 32-col tiles per strip (512 cols)
#define NSTRIP (N_SZ / (CT * 32))  // 16 col strips

constexpr float TEMP = 0.5f;
constexpr float EPS = 1e-8f;
// exp(dot/TEMP) = exp2(dot * log2(e)/TEMP); sqrt of the scale folded into
// BOTH normalized vectors so the MFMA accumulator is directly the exp2 arg.
constexpr float SQS = 1.6986436006556212f;  // sqrt(log2(e)/TEMP)

typedef short short8 __attribute__((ext_vector_type(8)));
typedef float f32x16 __attribute__((ext_vector_type(16)));

// Tiled pn layout (bf16): byte addr of element (row r, col d) =
//   (r>>5)*8192 + (d>>3)*512 + (r&31)*16 + (d&7)*2
// -> each MFMA fragment chunk is 512B contiguous across 32 lanes; a whole
//    32-row tile is one contiguous 8KB block.

// ---------------------------------------------------------------------------
// Kernel A: per wave, handle row pair (r, r+B). Normalize into tiled-bf16 pn
// (scaled by SQS); exact-f32 positive-pair term -> posbuf[block];
// selfexp[r] = exp2(self-sim of the ROUNDED bf16 row) for later diag removal.
// Block 0 thread 0 also zeroes the output accumulator (replaces memset node).
// ---------------------------------------------------------------------------
__global__ void norm_pos_kernel(const float* __restrict__ z_i,
                                const float* __restrict__ z_j,
                                unsigned int* __restrict__ pn_u32,
                                float* __restrict__ posbuf,
                                float* __restrict__ selfexp,
                                float* __restrict__ out) {
    __shared__ float sp[4];
    int wid = threadIdx.x >> 6;
    int lane = threadIdx.x & 63;
    int r = blockIdx.x * 4 + wid;                 // [0, B)
    if (blockIdx.x == 0 && threadIdx.x == 0) out[0] = 0.0f;
    float2 vi = *reinterpret_cast<const float2*>(z_i + (size_t)r * D_SZ + lane * 2);
    float2 vj = *reinterpret_cast<const float2*>(z_j + (size_t)r * D_SZ + lane * 2);
    float ssi = vi.x * vi.x + vi.y * vi.y;
    float ssj = vj.x * vj.x + vj.y * vj.y;
    float dot = vi.x * vj.x + vi.y * vj.y;
#pragma unroll
    for (int m = 32; m >= 1; m >>= 1) {
        ssi += __shfl_xor(ssi, m, 64);
        ssj += __shfl_xor(ssj, m, 64);
        dot += __shfl_xor(dot, m, 64);
    }
    float ni = fmaxf(sqrtf(ssi), EPS);
    float nj = fmaxf(sqrtf(ssj), EPS);
    float si = SQS / ni, sj = SQS / nj;
    union { unsigned int u32; __hip_bfloat16 h[2]; } pki, pkj;
    pki.h[0] = __float2bfloat16(vi.x * si);
    pki.h[1] = __float2bfloat16(vi.y * si);
    pkj.h[0] = __float2bfloat16(vj.x * sj);
    pkj.h[1] = __float2bfloat16(vj.y * sj);
    // tiled store: lane l holds cols 2l, 2l+1 (one u32)
    int u = ((r >> 5) * 2048) + ((lane >> 2) * 128) + ((r & 31) * 4) + (lane & 3);
    pn_u32[u] = pki.u32;
    int r2 = r + B_SZ;
    int u2 = ((r2 >> 5) * 2048) + ((lane >> 2) * 128) + ((r2 & 31) * 4) + (lane & 3);
    pn_u32[u2] = pkj.u32;
    // self-similarity of the rounded rows (exp2 units, same scale as MFMA)
    float bx = __bfloat162float(pki.h[0]), by = __bfloat162float(pki.h[1]);
    float cx = __bfloat162float(pkj.h[0]), cy = __bfloat162float(pkj.h[1]);
    float sdi = bx * bx + by * by;
    float sdj = cx * cx + cy * cy;
#pragma unroll
    for (int m = 32; m >= 1; m >>= 1) {
        sdi += __shfl_xor(sdi, m, 64);
        sdj += __shfl_xor(sdj, m, 64);
    }
    if (lane == 0) {
        selfexp[r] = __builtin_amdgcn_exp2f(sdi);
        selfexp[r2] = __builtin_amdgcn_exp2f(sdj);
        sp[wid] = -dot / (ni * nj * TEMP) / (float)B_SZ;
    }
    __syncthreads();
    if (threadIdx.x == 0)
        posbuf[blockIdx.x] = sp[0] + sp[1] + sp[2] + sp[3];
}

// ---------------------------------------------------------------------------
// Kernel B: partial[r][strip] = sum over the strip's 512 cols of exp2(sim)
// (diagonal INCLUDED — removed later via selfexp).
// Block = 2 waves x 2 row-tiles (128 rows) x 512-col strip; 1024 blocks =
// fully resident (4 blocks/CU). STATICALLY DISTINCT double buffers bufA/bufB
// (literal indices via 2-step unrolled loop) so the compiler can prove the
// global_load_lds writes don't alias the current ds_reads -> no spurious
// vmcnt(0) drain before the MFMA chain. XCD-bijective swizzle: each XCD
// owns 2 col-strips. C/D: col=lane&31, row=(reg&3)+8*(reg>>2)+4*(lane>>5).
// ---------------------------------------------------------------------------
__global__ __launch_bounds__(128, 2)
void simexp_kernel(const char* __restrict__ p, float* __restrict__ partial) {
    __shared__ char bufA[8192];
    __shared__ char bufB[8192];
    int wid = threadIdx.x >> 6;
    int lane = threadIdx.x & 63;
    int half = lane >> 5, lc = lane & 31;

    // XCD swizzle: 1024 blocks, 8 XCDs -> XCD k gets swz in [128k, 128k+128)
    // = col strips {2k, 2k+1} only.
    int swz = (blockIdx.x & 7) * 128 + (blockIdx.x >> 3);
    int strip = swz >> 6;          // [0,16)
    int bx = swz & 63;             // [0,64)
    int rt0 = bx * 4 + wid * 2;    // wave owns row-tiles rt0, rt0+1
    int ct0 = strip * CT;

    // A fragments: coalesced 1KB loads, held for the whole kernel
    const char* afrag = p + (size_t)rt0 * 8192 + half * 512 + lc * 16;
    short8 a0[8], a1[8];
#pragma unroll
    for (int kc = 0; kc < 8; ++kc) {
        a0[kc] = *reinterpret_cast<const short8*>(afrag + kc * 1024);
        a1[kc] = *reinterpret_cast<const short8*>(afrag + 8192 + kc * 1024);
    }

    float rs0[16], rs1[16];
#pragma unroll
    for (int i = 0; i < 16; ++i) { rs0[i] = 0.0f; rs1[i] = 0.0f; }

    // each wave stages 4 of the 8 1KB segments of one 8KB col-tile
    auto stageHalf = [&](char* buf, int ct) {
#pragma unroll
        for (int i = 0; i < 4; ++i) {
            int seg = wid * 4 + i;
            const char* g = p + (size_t)ct * 8192 + seg * 1024 + lane * 16;
            __builtin_amdgcn_global_load_lds(
                (const __attribute__((address_space(1))) unsigned int*)g,
                (__attribute__((address_space(3))) unsigned int*)(buf + seg * 1024),
                16, 0, 0);
        }
    };

    auto compute = [&](const char* buf) {
        const char* bb = buf + half * 512 + lc * 16;
        short8 b[8];
#pragma unroll
        for (int kc = 0; kc < 8; ++kc)
            b[kc] = *reinterpret_cast<const short8*>(bb + kc * 1024);
        f32x16 acc0 = {}, acc1 = {};
#pragma unroll
        for (int kc = 0; kc < 8; ++kc) {
            acc0 = __builtin_amdgcn_mfma_f32_32x32x16_bf16(a0[kc], b[kc], acc0, 0, 0, 0);
            acc1 = __builtin_amdgcn_mfma_f32_32x32x16_bf16(a1[kc], b[kc], acc1, 0, 0, 0);
        }
#pragma unroll
        for (int r = 0; r < 16; ++r) {
            rs0[r] += __builtin_amdgcn_exp2f(acc0[r]);
            rs1[r] += __builtin_amdgcn_exp2f(acc1[r]);
        }
    };

    stageHalf(bufA, ct0);
    __syncthreads();

#pragma unroll 1
    for (int t = 0; t < CT; t += 2) {
        if (t + 1 < CT) stageHalf(bufB, ct0 + t + 1);
        compute(bufA);               // reads bufA; writes went to bufB
        __syncthreads();             // drains own stage (issued ~1 phase ago)
        if (t + 2 < CT) stageHalf(bufA, ct0 + t + 2);
        compute(bufB);
        __syncthreads();
    }

    // reduce across the 32 column lanes
#pragma unroll
    for (int m = 1; m <= 16; m <<= 1) {
#pragma unroll
        for (int r = 0; r < 16; ++r) {
            rs0[r] += __shfl_xor(rs0[r], m, 64);
            rs1[r] += __shfl_xor(rs1[r], m, 64);
        }
    }
    if (lc == 0) {
#pragma unroll
        for (int r = 0; r < 16; ++r) {
            int lrow = (r & 3) + 8 * (r >> 2) + 4 * half;
            partial[(size_t)(rt0 * 32 + lrow) * NSTRIP + strip] = rs0[r];
            partial[(size_t)((rt0 + 1) * 32 + lrow) * NSTRIP + strip] = rs1[r];
        }
    }
}

// ---------------------------------------------------------------------------
// Kernel C: loss = sum(log(rowsum - selfexp))/2B + pos partials.
// 128 blocks x 64 threads; partial is [row][strip] -> 64B contiguous/thread.
// ---------------------------------------------------------------------------
__global__ void lse_kernel(const float* __restrict__ partial,
                           const float* __restrict__ selfexp,
                           const float* __restrict__ posbuf,
                           float* __restrict__ out) {
    int r = blockIdx.x * 64 + threadIdx.x;
    const float4* pr = reinterpret_cast<const float4*>(partial + (size_t)r * NSTRIP);
    float4 q0 = pr[0], q1 = pr[1], q2 = pr[2], q3 = pr[3];
    float s = (q0.x + q0.y + q0.z + q0.w) + (q1.x + q1.y + q1.z + q1.w) +
              (q2.x + q2.y + q2.z + q2.w) + (q3.x + q3.y + q3.z + q3.w);
    s -= selfexp[r];
    float v = __logf(s) * (1.0f / (float)N_SZ);
    if (threadIdx.x < 8) v += posbuf[blockIdx.x * 8 + threadIdx.x];
#pragma unroll
    for (int m = 32; m >= 1; m >>= 1) v += __shfl_xor(v, m, 64);
    if (threadIdx.x == 0)
        atomicAdd(out, v);
}

// ---------------------------------------------------------------------------
extern "C" void kernel_launch(void* const* d_in, const int* in_sizes, int n_in,
                              void* d_out, int out_size, void* d_ws, size_t ws_size,
                              hipStream_t stream) {
    const float* z_i = (const float*)d_in[0];
    const float* z_j = (const float*)d_in[1];
    float* out = (float*)d_out;
    char* ws = (char*)d_ws;

    unsigned int* pn = (unsigned int*)ws;                            // 2 MiB
    float* partial = (float*)(ws + (size_t)N_SZ * D_SZ * 2);         // 512 KiB
    float* selfexp = partial + (size_t)NSTRIP * N_SZ;                // 32 KiB
    float* posbuf = selfexp + N_SZ;                                  // 4 KiB

    norm_pos_kernel<<<B_SZ / 4, 256, 0, stream>>>(z_i, z_j, pn, posbuf,
                                                  selfexp, out);

    simexp_kernel<<<1024, 128, 0, stream>>>((const char*)pn, partial);

    lse_kernel<<<N_SZ / 64, 64, 0, stream>>>(partial, selfexp, posbuf, out);
}